// Round 19
// baseline (1355.612 us; speedup 1.0000x reference)
//
#include <hip/hip_runtime.h>

// GCN: x1 = relu(Agg(x@W1)+b1); x2 = relu(Agg(x1@W2)+b2); out = [x1,x2]@linW + linb
// Agg via CSR + per-node wave gather-reduce (R12 structure, locked).
// h, x1, x2 packed bf16. GEMMs: plain bf16 MFMA.
// R19: CSR fill split into (a) wave-aggregated bucket-append by dst-range
// (one atomic + contiguous 8B writes per wave -> no line ping-pong), fused
// with gemm1; (b) XCD-local fill: block b=blockIdx%8 handles bucket b, so
// every csr/cursor line is written by ONE XCD (was: 16 writers x 8 XCDs ->
// 66 MB write traffic for 3.2 MB payload). Agg blocks 128-thr (2 nodes).

#define D128 128

typedef __attribute__((ext_vector_type(8))) short bf16x8;
typedef __attribute__((ext_vector_type(4))) float f32x4;

__device__ __forceinline__ unsigned short f2bf_bits(float v) {
    unsigned int u = __float_as_uint(v);
    unsigned int r = u + 0x7FFFu + ((u >> 16) & 1u);   // RNE
    return (unsigned short)(r >> 16);
}
__device__ __forceinline__ float bflo(unsigned int u) { return __uint_as_float(u << 16); }
__device__ __forceinline__ float bfhi(unsigned int u) { return __uint_as_float(u & 0xFFFF0000u); }

// ---------- degree count: 4 edges/thread ----------
__global__ void k_count(const int* __restrict__ dst, int* __restrict__ indeg, int E) {
    int base = (blockIdx.x * 256 + threadIdx.x) * 4;
    if (base + 3 < E) {
        int4 d = *(const int4*)&dst[base];
        atomicAdd(&indeg[d.x], 1);
        atomicAdd(&indeg[d.y], 1);
        atomicAdd(&indeg[d.z], 1);
        atomicAdd(&indeg[d.w], 1);
    } else {
        for (int e = base; e < E; ++e) atomicAdd(&indeg[dst[e]], 1);
    }
}

// ---------- scan1: block-local exclusive scan + dinv ----------
__global__ void k_scan1(const int* __restrict__ indeg, int* __restrict__ row_ptr,
                        int* __restrict__ bsum, float* __restrict__ dinv, int n) {
    __shared__ int tmp[256];
    int i = blockIdx.x * 256 + threadIdx.x;
    int v = (i < n) ? indeg[i] : 0;
    if (i < n) dinv[i] = rsqrtf((float)(v + 1));  // +1 self loop
    tmp[threadIdx.x] = v;
    __syncthreads();
    for (int off = 1; off < 256; off <<= 1) {
        int t = (threadIdx.x >= off) ? tmp[threadIdx.x - off] : 0;
        __syncthreads();
        tmp[threadIdx.x] += t;
        __syncthreads();
    }
    if (i < n) row_ptr[i] = tmp[threadIdx.x] - v;
    if (threadIdx.x == 255) bsum[blockIdx.x] = tmp[255];
}

// ---------- scan23: global offsets; init cursor + bucket cursors ----------
__global__ void k_scan23(int* __restrict__ row_ptr, const int* __restrict__ bsum,
                         int* __restrict__ cursor, int* __restrict__ bcur,
                         int n, int E, int nb, int bchunk) {
    __shared__ int tmp[256];
    __shared__ int exc[256];
    int t = threadIdx.x;
    int v = (t < nb) ? bsum[t] : 0;
    tmp[t] = v;
    __syncthreads();
    for (int off = 1; off < 256; off <<= 1) {
        int x = (t >= off) ? tmp[t - off] : 0;
        __syncthreads();
        tmp[t] += x;
        __syncthreads();
    }
    exc[t] = tmp[t] - v;
    __syncthreads();
    int add = exc[blockIdx.x];
    int i = blockIdx.x * 256 + t;
    if (i < n) {
        int r = row_ptr[i] + add;
        row_ptr[i] = r;
        cursor[i] = r;
        if ((i % bchunk) == 0 && (i / bchunk) < 8) bcur[i / bchunk] = r;
    }
    if (blockIdx.x == 0 && t == 0) row_ptr[n] = E;
}

// ---------- aggregate + bias + relu ; h packed bf16x2 -> out packed bf16x2 ----------
// 128-thread blocks: 2 nodes/block (finer retirement granularity, Poisson degs).
__global__ __launch_bounds__(128) void k_agg_csr(
    const unsigned int* __restrict__ h, const int* __restrict__ row_ptr,
    const int* __restrict__ csr_src, const float* __restrict__ dinv,
    const float* __restrict__ bias, unsigned int* __restrict__ o, int n)
{
    int node = blockIdx.x * 2 + (threadIdx.x >> 6);
    int lane = threadIdx.x & 63;
    if (node >= n) return;
    float dv = dinv[node];
    unsigned int su = h[node * 64 + lane];
    float ax = dv * bflo(su);
    float ay = dv * bfhi(su);
    int j = row_ptr[node], end = row_ptr[node + 1];
    for (; j + 7 < end; j += 8) {
        int s0 = csr_src[j+0], s1 = csr_src[j+1], s2 = csr_src[j+2], s3 = csr_src[j+3];
        int s4 = csr_src[j+4], s5 = csr_src[j+5], s6 = csr_src[j+6], s7 = csr_src[j+7];
        float d0 = dinv[s0], d1 = dinv[s1], d2 = dinv[s2], d3 = dinv[s3];
        float d4 = dinv[s4], d5 = dinv[s5], d6 = dinv[s6], d7 = dinv[s7];
        unsigned int u0 = h[s0 * 64 + lane];
        unsigned int u1 = h[s1 * 64 + lane];
        unsigned int u2 = h[s2 * 64 + lane];
        unsigned int u3 = h[s3 * 64 + lane];
        unsigned int u4 = h[s4 * 64 + lane];
        unsigned int u5 = h[s5 * 64 + lane];
        unsigned int u6 = h[s6 * 64 + lane];
        unsigned int u7 = h[s7 * 64 + lane];
        ax += d0*bflo(u0) + d1*bflo(u1) + d2*bflo(u2) + d3*bflo(u3)
            + d4*bflo(u4) + d5*bflo(u5) + d6*bflo(u6) + d7*bflo(u7);
        ay += d0*bfhi(u0) + d1*bfhi(u1) + d2*bfhi(u2) + d3*bfhi(u3)
            + d4*bfhi(u4) + d5*bfhi(u5) + d6*bfhi(u6) + d7*bfhi(u7);
    }
    for (; j + 3 < end; j += 4) {
        int s0 = csr_src[j+0], s1 = csr_src[j+1], s2 = csr_src[j+2], s3 = csr_src[j+3];
        float d0 = dinv[s0], d1 = dinv[s1], d2 = dinv[s2], d3 = dinv[s3];
        unsigned int u0 = h[s0 * 64 + lane];
        unsigned int u1 = h[s1 * 64 + lane];
        unsigned int u2 = h[s2 * 64 + lane];
        unsigned int u3 = h[s3 * 64 + lane];
        ax += d0*bflo(u0) + d1*bflo(u1) + d2*bflo(u2) + d3*bflo(u3);
        ay += d0*bfhi(u0) + d1*bfhi(u1) + d2*bfhi(u2) + d3*bfhi(u3);
    }
    for (; j < end; ++j) {
        int s = csr_src[j];
        float d = dinv[s];
        unsigned int u = h[s * 64 + lane];
        ax += d * bflo(u);
        ay += d * bfhi(u);
    }
    float2 bv = ((const float2*)bias)[lane];
    unsigned int lo = f2bf_bits(fmaxf(dv * ax + bv.x, 0.f));
    unsigned int hi = f2bf_bits(fmaxf(dv * ay + bv.y, 0.f));
    o[node * 64 + lane] = lo | (hi << 16);
}

// ---------- MFMA GEMM building blocks ----------
__device__ __forceinline__ void stage_A_tile_f32(
    const float* __restrict__ A, int brow, int n, int tid,
    unsigned short* __restrict__ Ah)
{
    const float4* A4 = (const float4*)(A + (size_t)brow * D128);
#pragma unroll
    for (int it = 0; it < 8; ++it) {
        int f = it * 256 + tid;
        int r = f >> 5, k4 = f & 31;
        float4 v = make_float4(0.f, 0.f, 0.f, 0.f);
        if (brow + r < n) v = A4[f];
        int lane_ = (r & 15) + 16 * ((k4 >> 1) & 3);
        int base = ((((k4 >> 3) * 4 + (r >> 4)) * 64 + lane_) << 3) + (k4 & 1) * 4;
        ushort4 hh;
        unsigned short* hp = (unsigned short*)&hh;
        hp[0] = f2bf_bits(v.x); hp[1] = f2bf_bits(v.y);
        hp[2] = f2bf_bits(v.z); hp[3] = f2bf_bits(v.w);
        *(ushort4*)&Ah[base] = hh;
    }
}

__device__ __forceinline__ void stage_A_tile_bf16(
    const unsigned short* __restrict__ A, int brow, int n, int tid,
    unsigned short* __restrict__ Ah)
{
    const ushort4* A4 = (const ushort4*)(A + (size_t)brow * D128);
#pragma unroll
    for (int it = 0; it < 8; ++it) {
        int f = it * 256 + tid;
        int r = f >> 5, k4 = f & 31;
        ushort4 v = make_ushort4(0, 0, 0, 0);
        if (brow + r < n) v = A4[f];
        int lane_ = (r & 15) + 16 * ((k4 >> 1) & 3);
        int base = ((((k4 >> 3) * 4 + (r >> 4)) * 64 + lane_) << 3) + (k4 & 1) * 4;
        *(ushort4*)&Ah[base] = v;
    }
}

__device__ __forceinline__ void load_W_s(
    const float* __restrict__ W, int s, int colbase, int lanen, int kb,
    bf16x8 wh[2])
{
#pragma unroll
    for (int t = 0; t < 2; ++t)
#pragma unroll
        for (int j = 0; j < 8; ++j)
            wh[t][j] = (short)f2bf_bits(W[(size_t)(s * 32 + kb + j) * D128 + colbase + t * 16 + lanen]);
}

__device__ __forceinline__ void epilogue(
    f32x4 acc[4][2], float* __restrict__ C, const float* __restrict__ bias,
    int brow, int n, int colbase, int lanen, int l, int out_bf, int addC)
{
    float bv[2] = {0.f, 0.f};
    if (bias) { bv[0] = bias[colbase + lanen]; bv[1] = bias[colbase + 16 + lanen]; }
    int rsub = (l >> 4) * 4;
    if (out_bf) {
        unsigned short* Cb = (unsigned short*)C;
#pragma unroll
        for (int m = 0; m < 4; ++m)
#pragma unroll
            for (int t = 0; t < 2; ++t)
#pragma unroll
                for (int r = 0; r < 4; ++r) {
                    int row = brow + m * 16 + rsub + r;
                    if (row < n)
                        Cb[(size_t)row * D128 + colbase + t * 16 + lanen] = f2bf_bits(acc[m][t][r]);
                }
    } else {
#pragma unroll
        for (int m = 0; m < 4; ++m)
#pragma unroll
            for (int t = 0; t < 2; ++t)
#pragma unroll
                for (int r = 0; r < 4; ++r) {
                    int row = brow + m * 16 + rsub + r;
                    if (row < n) {
                        size_t idx = (size_t)row * D128 + colbase + t * 16 + lanen;
                        float v = acc[m][t][r] + bv[t];
                        if (addC) v += C[idx];
                        C[idx] = v;
                    }
                }
    }
}

__device__ __forceinline__ void gemm_compute(
    const float* __restrict__ W, f32x4 acc[4][2],
    int colbase, int lanen, int kb, int l,
    const unsigned short* __restrict__ Ah)
{
#pragma unroll
    for (int s = 0; s < 4; ++s) {
        bf16x8 wh[2];
        load_W_s(W, s, colbase, lanen, kb, wh);
#pragma unroll
        for (int m = 0; m < 4; ++m) {
            bf16x8 ah = *(const bf16x8*)&Ah[((s * 4 + m) * 64 + l) * 8];
#pragma unroll
            for (int t = 0; t < 2; ++t)
                acc[m][t] = __builtin_amdgcn_mfma_f32_16x16x32_bf16(ah, wh[t], acc[m][t], 0, 0, 0);
        }
    }
}

// ---------- fused: gemm1 (fp32 A) + bucket-append (wave-aggregated) ----------
__global__ __launch_bounds__(256, 2) void k_gemm1_bucket(
    const float* __restrict__ x, const float* __restrict__ W1,
    float* __restrict__ h, int n,
    const int* __restrict__ src, const int* __restrict__ dst,
    int* __restrict__ bcur, uint2* __restrict__ ebuf,
    int E, int bchunk, int gemmBlocks)
{
    __shared__ unsigned short Ah[4 * 4 * 64 * 8];   // 16 KB
    if (blockIdx.x < gemmBlocks) {
        int tid = threadIdx.x;
        int l = tid & 63, wv = tid >> 6;
        int brow = blockIdx.x * 64;
        int colbase = wv * 32, lanen = l & 15, kb = (l >> 4) * 8;
        f32x4 acc[4][2];
#pragma unroll
        for (int m = 0; m < 4; ++m)
#pragma unroll
            for (int t = 0; t < 2; ++t) acc[m][t] = (f32x4){0.f, 0.f, 0.f, 0.f};
        stage_A_tile_f32(x, brow, n, tid, Ah);
        __syncthreads();
        gemm_compute(W1, acc, colbase, lanen, kb, l, Ah);
        epilogue(acc, h, nullptr, brow, n, colbase, lanen, l, 1, 0);
    } else {
        int e = (blockIdx.x - gemmBlocks) * 256 + threadIdx.x;
        int lane = threadIdx.x & 63;
        bool valid = e < E;
        int s = 0, d = 0;
        if (valid) { s = src[e]; d = dst[e]; }
        int myb = valid ? (d / bchunk) : -1;
#pragma unroll
        for (int k = 0; k < 8; ++k) {
            unsigned long long m = __ballot(myb == k);
            if (m == 0ull) continue;
            int leader = __ffsll((long long)m) - 1;
            int base = 0;
            if (lane == leader) base = atomicAdd(&bcur[k], __popcll(m));
            base = __shfl(base, leader);
            if (myb == k) {
                int rank = __popcll(m & ((1ull << lane) - 1ull));
                ebuf[base + rank] = make_uint2((unsigned)s, (unsigned)d);
            }
        }
    }
}

// ---------- XCD-local fill: block's bucket = blockIdx % 8 ----------
__global__ __launch_bounds__(256) void k_fill2(
    const uint2* __restrict__ ebuf, const int* __restrict__ row_ptr,
    int* __restrict__ cursor, int* __restrict__ csr_src,
    int n, int bchunk, int K)
{
    int b = blockIdx.x & 7;          // XCD round-robin heuristic
    int slice = blockIdx.x >> 3;     // 0..K-1
    int lo = b * bchunk;
    int hi = (b + 1) * bchunk; if (hi > n) hi = n;
    int bstart = row_ptr[lo];
    int bend = row_ptr[hi];
    for (int i = bstart + slice * 256 + (int)threadIdx.x; i < bend; i += K * 256) {
        uint2 e = ebuf[i];
        int pos = atomicAdd(&cursor[e.y], 1);
        csr_src[pos] = (int)e.x;
    }
}

// ---------- gemm3b: A = bf16 x2; out += x2@linW_bot + bias ----------
__global__ __launch_bounds__(256, 2) void k_gemm_bf16A(
    const unsigned short* __restrict__ A, const float* __restrict__ W,
    const float* __restrict__ bias, float* __restrict__ C, int n)
{
    __shared__ unsigned short Ah[4 * 4 * 64 * 8];
    int tid = threadIdx.x;
    int l = tid & 63, wv = tid >> 6;
    int brow = blockIdx.x * 64;
    int colbase = wv * 32, lanen = l & 15, kb = (l >> 4) * 8;
    f32x4 acc[4][2];
#pragma unroll
    for (int m = 0; m < 4; ++m)
#pragma unroll
        for (int t = 0; t < 2; ++t) acc[m][t] = (f32x4){0.f, 0.f, 0.f, 0.f};
    stage_A_tile_bf16(A, brow, n, tid, Ah);
    __syncthreads();
    gemm_compute(W, acc, colbase, lanen, kb, l, Ah);
    epilogue(acc, C, bias, brow, n, colbase, lanen, l, 0, 1);
}

// ---------- dual: A = bf16 x1; h2 = bf16(x1@W2), p = x1@linW_top ----------
__global__ __launch_bounds__(256, 2) void k_gemm_dual(
    const unsigned short* __restrict__ A, const float* __restrict__ W2,
    const float* __restrict__ Wtop, float* __restrict__ hOut,
    float* __restrict__ pOut, int n)
{
    __shared__ unsigned short Ah[4 * 4 * 64 * 8];
    int tid = threadIdx.x;
    int l = tid & 63, wv = tid >> 6;
    int brow = blockIdx.x * 64;
    int colbase = wv * 32, lanen = l & 15, kb = (l >> 4) * 8;

    f32x4 accA[4][2], accB[4][2];
#pragma unroll
    for (int m = 0; m < 4; ++m)
#pragma unroll
        for (int t = 0; t < 2; ++t) {
            accA[m][t] = (f32x4){0.f, 0.f, 0.f, 0.f};
            accB[m][t] = (f32x4){0.f, 0.f, 0.f, 0.f};
        }

    stage_A_tile_bf16(A, brow, n, tid, Ah);
    __syncthreads();

#pragma unroll
    for (int s = 0; s < 4; ++s) {
        bf16x8 whA[2], whB[2];
        load_W_s(W2, s, colbase, lanen, kb, whA);
        load_W_s(Wtop, s, colbase, lanen, kb, whB);
#pragma unroll
        for (int m = 0; m < 4; ++m) {
            bf16x8 ah = *(const bf16x8*)&Ah[((s * 4 + m) * 64 + l) * 8];
#pragma unroll
            for (int t = 0; t < 2; ++t) {
                accA[m][t] = __builtin_amdgcn_mfma_f32_16x16x32_bf16(ah, whA[t], accA[m][t], 0, 0, 0);
                accB[m][t] = __builtin_amdgcn_mfma_f32_16x16x32_bf16(ah, whB[t], accB[m][t], 0, 0, 0);
            }
        }
    }
    epilogue(accA, hOut, nullptr, brow, n, colbase, lanen, l, 1, 0);
    epilogue(accB, pOut, nullptr, brow, n, colbase, lanen, l, 0, 0);
}

extern "C" void kernel_launch(void* const* d_in, const int* in_sizes, int n_in,
                              void* d_out, int out_size, void* d_ws, size_t ws_size,
                              hipStream_t stream) {
    const float* x    = (const float*)d_in[0];
    const int*   ei   = (const int*)d_in[1];
    const float* W1   = (const float*)d_in[2];
    const float* b1   = (const float*)d_in[3];
    const float* W2   = (const float*)d_in[4];
    const float* b2   = (const float*)d_in[5];
    const float* linW = (const float*)d_in[6];
    const float* linb = (const float*)d_in[7];

    int n = in_sizes[0] / D128;
    int E = in_sizes[1] / 2;
    const int* src = ei;
    const int* dst = ei + E;

    float* out = (float*)d_out;
    float* ws  = (float*)d_ws;

    // ws (4B words): csr_src[E] | indeg[n] | dinv[n] | row_ptr[n+1] | bsum[256]
    //   | bcur[8] | cursor[n] | align | ebuf[2E] | x1[n*64] | x2[n*64] | h[n*64]
    size_t o = 0;
    int*   csr_src = (int*)(ws + o);    o += E;
    int*   indeg   = (int*)(ws + o);    o += n;
    float* dinv    = ws + o;            o += n;
    int*   row_ptr = (int*)(ws + o);    o += n + 1;
    int*   bsum    = (int*)(ws + o);    o += 256;
    int*   bcur    = (int*)(ws + o);    o += 8;
    int*   cursor  = (int*)(ws + o);    o += n;
    o = (o + 3) & ~(size_t)3;
    uint2* ebuf    = (uint2*)(ws + o);  o += 2 * (size_t)E;
    unsigned int* x1 = (unsigned int*)(ws + o);  o += (size_t)n * 64;
    unsigned int* x2 = (unsigned int*)(ws + o);  o += (size_t)n * 64;
    float* h         = ws + o;                   // bf16-packed, n*64 uints

    int gn = (n + 255) / 256;
    int gE  = (E + 255) / 256;          // bucket append: 1 edge/thread
    int gE4 = (E + 1023) / 1024;        // count: 4 edges/thread
    int gemmBlocks = (n + 63) / 64;
    int aggBlocks  = (n + 1) / 2;       // 128-thr blocks, 2 nodes
    int bchunk = (n + 7) / 8;
    int K = 192;                        // fill slices per bucket

    // CSR prep
    (void)hipMemsetAsync(indeg, 0, (size_t)n * sizeof(int), stream);
    k_count<<<gE4, 256, 0, stream>>>(dst, indeg, E);
    k_scan1<<<gn, 256, 0, stream>>>(indeg, row_ptr, bsum, dinv, n);
    k_scan23<<<gn, 256, 0, stream>>>(row_ptr, bsum, cursor, bcur, n, E, gn, bchunk);

    // gemm1 (h = bf16(x@W1)) fused with bucket-append
    k_gemm1_bucket<<<gemmBlocks + gE, 256, 0, stream>>>(
        x, W1, h, n, src, dst, bcur, ebuf, E, bchunk, gemmBlocks);

    // XCD-local CSR fill
    k_fill2<<<8 * K, 256, 0, stream>>>(ebuf, row_ptr, cursor, csr_src, n, bchunk, K);

    // layer 1 aggregate -> x1 (bf16)
    k_agg_csr<<<aggBlocks, 128, 0, stream>>>((const unsigned int*)h, row_ptr, csr_src, dinv, b1, x1, n);

    // layer 2 gemm + first half of final linear (A = bf16 x1)
    k_gemm_dual<<<gemmBlocks, 256, 0, stream>>>((const unsigned short*)x1, W2, linW, h, out, n);

    // layer 2 aggregate -> x2 (bf16)
    k_agg_csr<<<aggBlocks, 128, 0, stream>>>((const unsigned int*)h, row_ptr, csr_src, dinv, b2, x2, n);

    // final: out += x2 @ linW[128:256] + linb
    k_gemm_bf16A<<<gemmBlocks, 256, 0, stream>>>((const unsigned short*)x2, linW + 128 * D128, linb, out, n);
}

// Round 20
// 224.263 us; speedup vs baseline: 6.0447x; 6.0447x over previous
//
#include <hip/hip_runtime.h>

// GCN: x1 = relu(Agg(x@W1)+b1); x2 = relu(Agg(x1@W2)+b2); out = [x1,x2]@linW + linb
// == R18 structure (224.5us best) ==
// Agg via CSR (counting sort) + per-node wave gather-reduce; h/x1/x2 packed bf16.
// GEMMs plain bf16 MFMA; gemm1 fused with CSR fill; dual shares A-staging.
// Locked floors (each >=2 failed restructures): agg ~40us x2 (R13/R14/R17),
// fill ~47us fused (R16 null, R19 bucket-atomic disaster: 8 global counters
// ping-pong across XCDs = serialization). R20 delta: agg blocks 128-thr/2-node
// (finer retirement granularity; only untested piece of R19).

#define D128 128

typedef __attribute__((ext_vector_type(8))) short bf16x8;
typedef __attribute__((ext_vector_type(4))) float f32x4;

__device__ __forceinline__ unsigned short f2bf_bits(float v) {
    unsigned int u = __float_as_uint(v);
    unsigned int r = u + 0x7FFFu + ((u >> 16) & 1u);   // RNE
    return (unsigned short)(r >> 16);
}
__device__ __forceinline__ float bflo(unsigned int u) { return __uint_as_float(u << 16); }
__device__ __forceinline__ float bfhi(unsigned int u) { return __uint_as_float(u & 0xFFFF0000u); }

// ---------- degree count: 4 edges/thread ----------
__global__ void k_count(const int* __restrict__ dst, int* __restrict__ indeg, int E) {
    int base = (blockIdx.x * 256 + threadIdx.x) * 4;
    if (base + 3 < E) {
        int4 d = *(const int4*)&dst[base];
        atomicAdd(&indeg[d.x], 1);
        atomicAdd(&indeg[d.y], 1);
        atomicAdd(&indeg[d.z], 1);
        atomicAdd(&indeg[d.w], 1);
    } else {
        for (int e = base; e < E; ++e) atomicAdd(&indeg[dst[e]], 1);
    }
}

// ---------- scan1: block-local exclusive scan + dinv ----------
__global__ void k_scan1(const int* __restrict__ indeg, int* __restrict__ row_ptr,
                        int* __restrict__ bsum, float* __restrict__ dinv, int n) {
    __shared__ int tmp[256];
    int i = blockIdx.x * 256 + threadIdx.x;
    int v = (i < n) ? indeg[i] : 0;
    if (i < n) dinv[i] = rsqrtf((float)(v + 1));  // +1 self loop
    tmp[threadIdx.x] = v;
    __syncthreads();
    for (int off = 1; off < 256; off <<= 1) {
        int t = (threadIdx.x >= off) ? tmp[threadIdx.x - off] : 0;
        __syncthreads();
        tmp[threadIdx.x] += t;
        __syncthreads();
    }
    if (i < n) row_ptr[i] = tmp[threadIdx.x] - v;
    if (threadIdx.x == 255) bsum[blockIdx.x] = tmp[255];
}

// ---------- scan23: every block redundantly scans bsum, applies offset ----------
__global__ void k_scan23(int* __restrict__ row_ptr, const int* __restrict__ bsum,
                         int* __restrict__ cursor, int n, int E, int nb) {
    __shared__ int tmp[256];
    __shared__ int exc[256];
    int t = threadIdx.x;
    int v = (t < nb) ? bsum[t] : 0;
    tmp[t] = v;
    __syncthreads();
    for (int off = 1; off < 256; off <<= 1) {
        int x = (t >= off) ? tmp[t - off] : 0;
        __syncthreads();
        tmp[t] += x;
        __syncthreads();
    }
    exc[t] = tmp[t] - v;
    __syncthreads();
    int add = exc[blockIdx.x];
    int i = blockIdx.x * 256 + t;
    if (i < n) {
        int r = row_ptr[i] + add;
        row_ptr[i] = r;
        cursor[i] = r;
    }
    if (blockIdx.x == 0 && t == 0) row_ptr[n] = E;
}

// ---------- aggregate + bias + relu ; h packed bf16x2 -> out packed bf16x2 ----------
// 128-thread blocks: 2 nodes/block (finer retirement under Poisson degree variance).
__global__ __launch_bounds__(128) void k_agg_csr(
    const unsigned int* __restrict__ h, const int* __restrict__ row_ptr,
    const int* __restrict__ csr_src, const float* __restrict__ dinv,
    const float* __restrict__ bias, unsigned int* __restrict__ o, int n)
{
    int node = blockIdx.x * 2 + (threadIdx.x >> 6);
    int lane = threadIdx.x & 63;
    if (node >= n) return;
    float dv = dinv[node];
    unsigned int su = h[node * 64 + lane];
    float ax = dv * bflo(su);
    float ay = dv * bfhi(su);
    int j = row_ptr[node], end = row_ptr[node + 1];
    for (; j + 7 < end; j += 8) {
        int s0 = csr_src[j+0], s1 = csr_src[j+1], s2 = csr_src[j+2], s3 = csr_src[j+3];
        int s4 = csr_src[j+4], s5 = csr_src[j+5], s6 = csr_src[j+6], s7 = csr_src[j+7];
        float d0 = dinv[s0], d1 = dinv[s1], d2 = dinv[s2], d3 = dinv[s3];
        float d4 = dinv[s4], d5 = dinv[s5], d6 = dinv[s6], d7 = dinv[s7];
        unsigned int u0 = h[s0 * 64 + lane];
        unsigned int u1 = h[s1 * 64 + lane];
        unsigned int u2 = h[s2 * 64 + lane];
        unsigned int u3 = h[s3 * 64 + lane];
        unsigned int u4 = h[s4 * 64 + lane];
        unsigned int u5 = h[s5 * 64 + lane];
        unsigned int u6 = h[s6 * 64 + lane];
        unsigned int u7 = h[s7 * 64 + lane];
        ax += d0*bflo(u0) + d1*bflo(u1) + d2*bflo(u2) + d3*bflo(u3)
            + d4*bflo(u4) + d5*bflo(u5) + d6*bflo(u6) + d7*bflo(u7);
        ay += d0*bfhi(u0) + d1*bfhi(u1) + d2*bfhi(u2) + d3*bfhi(u3)
            + d4*bfhi(u4) + d5*bfhi(u5) + d6*bfhi(u6) + d7*bfhi(u7);
    }
    for (; j + 3 < end; j += 4) {
        int s0 = csr_src[j+0], s1 = csr_src[j+1], s2 = csr_src[j+2], s3 = csr_src[j+3];
        float d0 = dinv[s0], d1 = dinv[s1], d2 = dinv[s2], d3 = dinv[s3];
        unsigned int u0 = h[s0 * 64 + lane];
        unsigned int u1 = h[s1 * 64 + lane];
        unsigned int u2 = h[s2 * 64 + lane];
        unsigned int u3 = h[s3 * 64 + lane];
        ax += d0*bflo(u0) + d1*bflo(u1) + d2*bflo(u2) + d3*bflo(u3);
        ay += d0*bfhi(u0) + d1*bfhi(u1) + d2*bfhi(u2) + d3*bfhi(u3);
    }
    for (; j < end; ++j) {
        int s = csr_src[j];
        float d = dinv[s];
        unsigned int u = h[s * 64 + lane];
        ax += d * bflo(u);
        ay += d * bfhi(u);
    }
    float2 bv = ((const float2*)bias)[lane];
    unsigned int lo = f2bf_bits(fmaxf(dv * ax + bv.x, 0.f));
    unsigned int hi = f2bf_bits(fmaxf(dv * ay + bv.y, 0.f));
    o[node * 64 + lane] = lo | (hi << 16);
}

// ---------- MFMA GEMM building blocks ----------
__device__ __forceinline__ void stage_A_tile_f32(
    const float* __restrict__ A, int brow, int n, int tid,
    unsigned short* __restrict__ Ah)
{
    const float4* A4 = (const float4*)(A + (size_t)brow * D128);
#pragma unroll
    for (int it = 0; it < 8; ++it) {
        int f = it * 256 + tid;
        int r = f >> 5, k4 = f & 31;
        float4 v = make_float4(0.f, 0.f, 0.f, 0.f);
        if (brow + r < n) v = A4[f];
        int lane_ = (r & 15) + 16 * ((k4 >> 1) & 3);
        int base = ((((k4 >> 3) * 4 + (r >> 4)) * 64 + lane_) << 3) + (k4 & 1) * 4;
        ushort4 hh;
        unsigned short* hp = (unsigned short*)&hh;
        hp[0] = f2bf_bits(v.x); hp[1] = f2bf_bits(v.y);
        hp[2] = f2bf_bits(v.z); hp[3] = f2bf_bits(v.w);
        *(ushort4*)&Ah[base] = hh;
    }
}

__device__ __forceinline__ void stage_A_tile_bf16(
    const unsigned short* __restrict__ A, int brow, int n, int tid,
    unsigned short* __restrict__ Ah)
{
    const ushort4* A4 = (const ushort4*)(A + (size_t)brow * D128);
#pragma unroll
    for (int it = 0; it < 8; ++it) {
        int f = it * 256 + tid;
        int r = f >> 5, k4 = f & 31;
        ushort4 v = make_ushort4(0, 0, 0, 0);
        if (brow + r < n) v = A4[f];
        int lane_ = (r & 15) + 16 * ((k4 >> 1) & 3);
        int base = ((((k4 >> 3) * 4 + (r >> 4)) * 64 + lane_) << 3) + (k4 & 1) * 4;
        *(ushort4*)&Ah[base] = v;
    }
}

__device__ __forceinline__ void load_W_s(
    const float* __restrict__ W, int s, int colbase, int lanen, int kb,
    bf16x8 wh[2])
{
#pragma unroll
    for (int t = 0; t < 2; ++t)
#pragma unroll
        for (int j = 0; j < 8; ++j)
            wh[t][j] = (short)f2bf_bits(W[(size_t)(s * 32 + kb + j) * D128 + colbase + t * 16 + lanen]);
}

__device__ __forceinline__ void epilogue(
    f32x4 acc[4][2], float* __restrict__ C, const float* __restrict__ bias,
    int brow, int n, int colbase, int lanen, int l, int out_bf, int addC)
{
    float bv[2] = {0.f, 0.f};
    if (bias) { bv[0] = bias[colbase + lanen]; bv[1] = bias[colbase + 16 + lanen]; }
    int rsub = (l >> 4) * 4;
    if (out_bf) {
        unsigned short* Cb = (unsigned short*)C;
#pragma unroll
        for (int m = 0; m < 4; ++m)
#pragma unroll
            for (int t = 0; t < 2; ++t)
#pragma unroll
                for (int r = 0; r < 4; ++r) {
                    int row = brow + m * 16 + rsub + r;
                    if (row < n)
                        Cb[(size_t)row * D128 + colbase + t * 16 + lanen] = f2bf_bits(acc[m][t][r]);
                }
    } else {
#pragma unroll
        for (int m = 0; m < 4; ++m)
#pragma unroll
            for (int t = 0; t < 2; ++t)
#pragma unroll
                for (int r = 0; r < 4; ++r) {
                    int row = brow + m * 16 + rsub + r;
                    if (row < n) {
                        size_t idx = (size_t)row * D128 + colbase + t * 16 + lanen;
                        float v = acc[m][t][r] + bv[t];
                        if (addC) v += C[idx];
                        C[idx] = v;
                    }
                }
    }
}

__device__ __forceinline__ void gemm_compute(
    const float* __restrict__ W, f32x4 acc[4][2],
    int colbase, int lanen, int kb, int l,
    const unsigned short* __restrict__ Ah)
{
#pragma unroll
    for (int s = 0; s < 4; ++s) {
        bf16x8 wh[2];
        load_W_s(W, s, colbase, lanen, kb, wh);
#pragma unroll
        for (int m = 0; m < 4; ++m) {
            bf16x8 ah = *(const bf16x8*)&Ah[((s * 4 + m) * 64 + l) * 8];
#pragma unroll
            for (int t = 0; t < 2; ++t)
                acc[m][t] = __builtin_amdgcn_mfma_f32_16x16x32_bf16(ah, wh[t], acc[m][t], 0, 0, 0);
        }
    }
}

// ---------- fused: gemm1 (fp32 A; blocks < gemmBlocks) + CSR fill ----------
__global__ __launch_bounds__(256, 2) void k_gemm1_fill(
    const float* __restrict__ x, const float* __restrict__ W1,
    float* __restrict__ h, int n,
    const int* __restrict__ src, const int* __restrict__ dst,
    int* __restrict__ cursor, int* __restrict__ csr_src,
    int E, int gemmBlocks)
{
    __shared__ unsigned short Ah[4 * 4 * 64 * 8];   // 16 KB
    if (blockIdx.x < gemmBlocks) {
        int tid = threadIdx.x;
        int l = tid & 63, wv = tid >> 6;
        int brow = blockIdx.x * 64;
        int colbase = wv * 32, lanen = l & 15, kb = (l >> 4) * 8;
        f32x4 acc[4][2];
#pragma unroll
        for (int m = 0; m < 4; ++m)
#pragma unroll
            for (int t = 0; t < 2; ++t) acc[m][t] = (f32x4){0.f, 0.f, 0.f, 0.f};
        stage_A_tile_f32(x, brow, n, tid, Ah);
        __syncthreads();
        gemm_compute(W1, acc, colbase, lanen, kb, l, Ah);
        epilogue(acc, h, nullptr, brow, n, colbase, lanen, l, 1, 0);
    } else {
        int e = (blockIdx.x - gemmBlocks) * 256 + threadIdx.x;
        if (e >= E) return;
        int s = src[e], d = dst[e];
        int pos = atomicAdd(&cursor[d], 1);
        csr_src[pos] = s;
    }
}

// ---------- gemm3b: A = bf16 x2; out += x2@linW_bot + bias ----------
__global__ __launch_bounds__(256, 2) void k_gemm_bf16A(
    const unsigned short* __restrict__ A, const float* __restrict__ W,
    const float* __restrict__ bias, float* __restrict__ C, int n)
{
    __shared__ unsigned short Ah[4 * 4 * 64 * 8];
    int tid = threadIdx.x;
    int l = tid & 63, wv = tid >> 6;
    int brow = blockIdx.x * 64;
    int colbase = wv * 32, lanen = l & 15, kb = (l >> 4) * 8;
    f32x4 acc[4][2];
#pragma unroll
    for (int m = 0; m < 4; ++m)
#pragma unroll
        for (int t = 0; t < 2; ++t) acc[m][t] = (f32x4){0.f, 0.f, 0.f, 0.f};
    stage_A_tile_bf16(A, brow, n, tid, Ah);
    __syncthreads();
    gemm_compute(W, acc, colbase, lanen, kb, l, Ah);
    epilogue(acc, C, bias, brow, n, colbase, lanen, l, 0, 1);
}

// ---------- dual: A = bf16 x1; h2 = bf16(x1@W2), p = x1@linW_top ----------
__global__ __launch_bounds__(256, 2) void k_gemm_dual(
    const unsigned short* __restrict__ A, const float* __restrict__ W2,
    const float* __restrict__ Wtop, float* __restrict__ hOut,
    float* __restrict__ pOut, int n)
{
    __shared__ unsigned short Ah[4 * 4 * 64 * 8];
    int tid = threadIdx.x;
    int l = tid & 63, wv = tid >> 6;
    int brow = blockIdx.x * 64;
    int colbase = wv * 32, lanen = l & 15, kb = (l >> 4) * 8;

    f32x4 accA[4][2], accB[4][2];
#pragma unroll
    for (int m = 0; m < 4; ++m)
#pragma unroll
        for (int t = 0; t < 2; ++t) {
            accA[m][t] = (f32x4){0.f, 0.f, 0.f, 0.f};
            accB[m][t] = (f32x4){0.f, 0.f, 0.f, 0.f};
        }

    stage_A_tile_bf16(A, brow, n, tid, Ah);
    __syncthreads();

#pragma unroll
    for (int s = 0; s < 4; ++s) {
        bf16x8 whA[2], whB[2];
        load_W_s(W2, s, colbase, lanen, kb, whA);
        load_W_s(Wtop, s, colbase, lanen, kb, whB);
#pragma unroll
        for (int m = 0; m < 4; ++m) {
            bf16x8 ah = *(const bf16x8*)&Ah[((s * 4 + m) * 64 + l) * 8];
#pragma unroll
            for (int t = 0; t < 2; ++t) {
                accA[m][t] = __builtin_amdgcn_mfma_f32_16x16x32_bf16(ah, whA[t], accA[m][t], 0, 0, 0);
                accB[m][t] = __builtin_amdgcn_mfma_f32_16x16x32_bf16(ah, whB[t], accB[m][t], 0, 0, 0);
            }
        }
    }
    epilogue(accA, hOut, nullptr, brow, n, colbase, lanen, l, 1, 0);
    epilogue(accB, pOut, nullptr, brow, n, colbase, lanen, l, 0, 0);
}

extern "C" void kernel_launch(void* const* d_in, const int* in_sizes, int n_in,
                              void* d_out, int out_size, void* d_ws, size_t ws_size,
                              hipStream_t stream) {
    const float* x    = (const float*)d_in[0];
    const int*   ei   = (const int*)d_in[1];
    const float* W1   = (const float*)d_in[2];
    const float* b1   = (const float*)d_in[3];
    const float* W2   = (const float*)d_in[4];
    const float* b2   = (const float*)d_in[5];
    const float* linW = (const float*)d_in[6];
    const float* linb = (const float*)d_in[7];

    int n = in_sizes[0] / D128;
    int E = in_sizes[1] / 2;
    const int* src = ei;
    const int* dst = ei + E;

    float* out = (float*)d_out;
    float* ws  = (float*)d_ws;

    // ws (4B words): csr_src[E] | indeg[n] | dinv[n] | row_ptr[n+1] | bsum[256]
    //                | cursor[n] | align | x1[n*64] | x2[n*64] | h[n*64] (bf16x2)
    size_t o = 0;
    int*   csr_src = (int*)(ws + o);    o += E;
    int*   indeg   = (int*)(ws + o);    o += n;
    float* dinv    = ws + o;            o += n;
    int*   row_ptr = (int*)(ws + o);    o += n + 1;
    int*   bsum    = (int*)(ws + o);    o += 256;
    int*   cursor  = (int*)(ws + o);    o += n;
    o = (o + 3) & ~(size_t)3;
    unsigned int* x1 = (unsigned int*)(ws + o);  o += (size_t)n * 64;
    unsigned int* x2 = (unsigned int*)(ws + o);  o += (size_t)n * 64;
    float* h         = ws + o;                   // bf16-packed, n*64 uints

    int gn = (n + 255) / 256;
    int gE  = (E + 255) / 256;          // fill: 1 edge/thread
    int gE4 = (E + 1023) / 1024;        // count: 4 edges/thread
    int gemmBlocks = (n + 63) / 64;
    int aggBlocks  = (n + 1) / 2;       // 128-thr blocks, 2 nodes

    // CSR prep
    (void)hipMemsetAsync(indeg, 0, (size_t)n * sizeof(int), stream);
    k_count<<<gE4, 256, 0, stream>>>(dst, indeg, E);
    k_scan1<<<gn, 256, 0, stream>>>(indeg, row_ptr, bsum, dinv, n);
    k_scan23<<<gn, 256, 0, stream>>>(row_ptr, bsum, cursor, n, E, gn);

    // gemm1 (h = bf16(x@W1)) fused with CSR fill
    k_gemm1_fill<<<gemmBlocks + gE, 256, 0, stream>>>(
        x, W1, h, n, src, dst, cursor, csr_src, E, gemmBlocks);

    // layer 1 aggregate -> x1 (bf16)
    k_agg_csr<<<aggBlocks, 128, 0, stream>>>((const unsigned int*)h, row_ptr, csr_src, dinv, b1, x1, n);

    // layer 2 gemm + first half of final linear (A = bf16 x1)
    k_gemm_dual<<<gemmBlocks, 256, 0, stream>>>((const unsigned short*)x1, W2, linW, h, out, n);

    // layer 2 aggregate -> x2 (bf16)
    k_agg_csr<<<aggBlocks, 128, 0, stream>>>((const unsigned int*)h, row_ptr, csr_src, dinv, b2, x2, n);

    // final: out += x2 @ linW[128:256] + linb
    k_gemm_bf16A<<<gemmBlocks, 256, 0, stream>>>((const unsigned short*)x2, linW + 128 * D128, linb, out, n);
}